// Round 4
// baseline (258.391 us; speedup 1.0000x reference)
//
#include <hip/hip_runtime.h>
#include <cfloat>
#include <climits>

// Retriever: cosine-sim top-5 over 100k knowledge vectors + gather.
// v4: sims = pure register-streamed bf16-MFMA (no LDS, no syncthreads, no tail),
// k-norms via MFMA self-product diagonal, scaled dots stored to ws;
// scan kernel does chunked top-8; rescore does exact f32 top-5 + gather.

#define BQ 64
#define DD 768
#define NK 100000
#define LK 32
#define K_TOP 5
#define BN 64                       // n rows per sims block
#define NB ((NK + BN - 1) / BN)     // 1563
#define SST (NB * BN)               // 100032, sims row stride
#define NCH 8                       // scan chunks per query
#define CHN (NK / NCH)              // 12500
#define M_CH 8                      // per-chunk top-M
#define T_CAND 16                   // rescore candidate count

typedef __attribute__((ext_vector_type(8))) short short8;
typedef __attribute__((ext_vector_type(4))) float f32x4;

// ---------- phase 0: query -> bf16 (trunc) + exact f32 norms ----------
__global__ __launch_bounds__(256) void prep_kernel(const float* __restrict__ q,
                                                   ushort* __restrict__ qbf,
                                                   float* __restrict__ qn) {
    int b = blockIdx.x, t = threadIdx.x;
    float s = 0.f;
    for (int k = t; k < DD; k += 256) {
        float v = q[b * DD + k];
        s += v * v;
        qbf[b * DD + k] = (ushort)(__float_as_uint(v) >> 16);
    }
    for (int off = 32; off > 0; off >>= 1) s += __shfl_down(s, off, 64);
    __shared__ float red[4];
    if ((t & 63) == 0) red[t >> 6] = s;
    __syncthreads();
    if (t == 0) qn[b] = sqrtf(red[0] + red[1] + red[2] + red[3]);
}

// ---------- phase 1: bf16 MFMA screening, pure stream ----------
// 1563 blocks x 4 waves; wave tile 32q x 32n; b depth-3 ring, a depth-2.
// Norms: ncc[nf] = mfma(bb,bb,ncc) accumulates Gram; diag = ||b||^2.
__global__ __launch_bounds__(256) void sims_kernel(const ushort* __restrict__ qbf,
                                                   const float* __restrict__ ke,
                                                   float* __restrict__ simsO) {
    const int t = threadIdx.x;
    const int w = t >> 6, l = t & 63;
    const int lg = l >> 4, li = l & 15;
    const int wq = w >> 1, wn = w & 1;
    const int n0 = blockIdx.x * BN;

    const ushort* aptr[2];
#pragma unroll
    for (int m = 0; m < 2; ++m)
        aptr[m] = qbf + (wq * 32 + m * 16 + li) * DD + lg * 8;
    const float* bptr[2];
#pragma unroll
    for (int nf = 0; nf < 2; ++nf) {
        int r = n0 + wn * 32 + nf * 16 + li;
        if (r >= NK) r = NK - 1;               // clamp; ignored by scan
        bptr[nf] = ke + (size_t)r * DD + lg * 8;
    }

    f32x4 acc[2][2], ncc[2];
#pragma unroll
    for (int m = 0; m < 2; ++m)
#pragma unroll
        for (int nf = 0; nf < 2; ++nf) acc[m][nf] = (f32x4){0.f, 0.f, 0.f, 0.f};
#pragma unroll
    for (int nf = 0; nf < 2; ++nf) ncc[nf] = (f32x4){0.f, 0.f, 0.f, 0.f};

    short8 a_r[2][2];
    f32x4  b_r[3][2][2];

#define LOADB(slot, step) do {                                             \
        const int ko_ = (step) * 32;                                       \
        _Pragma("unroll")                                                  \
        for (int nf_ = 0; nf_ < 2; ++nf_) {                                \
            b_r[slot][nf_][0] = *(const f32x4*)(bptr[nf_] + ko_);          \
            b_r[slot][nf_][1] = *(const f32x4*)(bptr[nf_] + ko_ + 4);      \
        }                                                                  \
    } while (0)
#define LOADA(slot, step) do {                                             \
        const int ko_ = (step) * 32;                                       \
        _Pragma("unroll")                                                  \
        for (int m_ = 0; m_ < 2; ++m_)                                     \
            a_r[slot][m_] = *(const short8*)(aptr[m_] + ko_);              \
    } while (0)

    LOADA(0, 0);
    LOADB(0, 0);
    LOADB(1, 1);

#pragma unroll
    for (int kt = 0; kt < 24; ++kt) {
        const int cb = kt % 3, ca = kt & 1;
        if (kt < 22) LOADB((kt + 2) % 3, kt + 2);
        if (kt < 23) LOADA(ca ^ 1, kt + 1);

        short8 bb[2];
#pragma unroll
        for (int nf = 0; nf < 2; ++nf) {
            union { short8 s8; uint u[4]; } pk;
#pragma unroll
            for (int p = 0; p < 4; ++p) {
                uint f0 = __float_as_uint(b_r[cb][nf][p >> 1][(p & 1) * 2 + 0]);
                uint f1 = __float_as_uint(b_r[cb][nf][p >> 1][(p & 1) * 2 + 1]);
                pk.u[p] = __builtin_amdgcn_perm(f1, f0, 0x07060302u);
            }
            bb[nf] = pk.s8;
        }
#pragma unroll
        for (int m = 0; m < 2; ++m)
#pragma unroll
            for (int nf = 0; nf < 2; ++nf)
                acc[m][nf] = __builtin_amdgcn_mfma_f32_16x16x32_bf16(
                    a_r[ca][m], bb[nf], acc[m][nf], 0, 0, 0);
#pragma unroll
        for (int nf = 0; nf < 2; ++nf)
            ncc[nf] = __builtin_amdgcn_mfma_f32_16x16x32_bf16(
                bb[nf], bb[nf], ncc[nf], 0, 0, 0);
    }
#undef LOADB
#undef LOADA

    // diag extract: C[li][li] held by lane (li>>2)*16+li in reg li&3
#pragma unroll
    for (int nf = 0; nf < 2; ++nf) {
        float x = ncc[nf][li & 3];
        float dsq = __shfl(x, ((li >> 2) << 4) | li, 64);
        float rkv = rsqrtf(dsq);
        const int ncol = n0 + wn * 32 + nf * 16 + li;
#pragma unroll
        for (int m = 0; m < 2; ++m)
#pragma unroll
            for (int r = 0; r < 4; ++r)
                simsO[(size_t)(wq * 32 + m * 16 + lg * 4 + r) * SST + ncol] =
                    acc[m][nf][r] * rkv;
    }
}

// ---------- phase 2: chunked top-8 scan of sims buffer ----------
#define INS8(v, n, va, ia)                                                  \
    _Pragma("unroll")                                                       \
    for (int m_ = 0; m_ < 8; ++m_) {                                        \
        if ((v) > va[m_]) {                                                 \
            float tv_ = va[m_]; va[m_] = (v); (v) = tv_;                    \
            int ti_ = ia[m_]; ia[m_] = (n); (n) = ti_;                      \
        }                                                                   \
    }

__global__ __launch_bounds__(256) void scan_kernel(const float* __restrict__ simsO,
                                                   float2* __restrict__ pv2) {
    const int t = threadIdx.x;
    const int q = blockIdx.x >> 3, c = blockIdx.x & 7;
    const int base = c * CHN;

    float v8[8]; int i8[8];
#pragma unroll
    for (int m = 0; m < 8; ++m) { v8[m] = -FLT_MAX; i8[m] = INT_MAX; }

    const float4* row = (const float4*)(simsO + (size_t)q * SST + base);
    for (int i4 = t; i4 < CHN / 4; i4 += 256) {   // 3125 float4s
        float4 vv = row[i4];
        int n0_ = base + i4 * 4;
        float v; int n;
        v = vv.x; n = n0_ + 0; INS8(v, n, v8, i8);
        v = vv.y; n = n0_ + 1; INS8(v, n, v8, i8);
        v = vv.z; n = n0_ + 2; INS8(v, n, v8, i8);
        v = vv.w; n = n0_ + 3; INS8(v, n, v8, i8);
    }

    __shared__ float sv[256][8];
    __shared__ int   si[256][8];
#pragma unroll
    for (int m = 0; m < 8; ++m) { sv[t][m] = v8[m]; si[t][m] = i8[m]; }
    __syncthreads();

    for (int active = 64; active >= 1; active >>= 2) {
        if (t < active) {
#pragma unroll
            for (int m = 0; m < 8; ++m) { v8[m] = -FLT_MAX; i8[m] = INT_MAX; }
            for (int s = 0; s < 4; ++s) {
                int rrow = t * 4 + s;
#pragma unroll
                for (int m = 0; m < 8; ++m) {
                    float v = sv[rrow][m]; int n = si[rrow][m];
                    INS8(v, n, v8, i8);
                }
            }
        }
        __syncthreads();
        if (t < active) {
#pragma unroll
            for (int m = 0; m < 8; ++m) { sv[t][m] = v8[m]; si[t][m] = i8[m]; }
        }
        __syncthreads();
    }

    if (t < M_CH)
        pv2[((size_t)q * NCH + c) * M_CH + t] =
            make_float2(sv[0][t], __int_as_float(si[0][t]));
}

// ---------- phase 3: merge 64 -> top-16 -> exact f32 rescore -> top-5 -> gather ----------
__global__ __launch_bounds__(256) void rescore_kernel(
    const float2* __restrict__ pv2,
    const float* __restrict__ q, const float* __restrict__ ke,
    const int* __restrict__ kf, const float* __restrict__ qn,
    float* __restrict__ out) {
    const int qi = blockIdx.x, t = threadIdx.x;
    __shared__ float sv[64];
    __shared__ int   si[64];
    __shared__ int   ci[T_CAND];
    __shared__ float cs_[T_CAND];
    __shared__ int   fi[K_TOP];

    if (t < NCH * M_CH) {
        float2 e = pv2[(size_t)qi * NCH * M_CH + t];
        sv[t] = e.x; si[t] = __float_as_int(e.y);
    }
    __syncthreads();

    if (t == 0) {
        float v16[T_CAND]; int i16[T_CAND];
#pragma unroll
        for (int m = 0; m < T_CAND; ++m) { v16[m] = -FLT_MAX; i16[m] = INT_MAX; }
        for (int c = 0; c < NCH * M_CH; ++c) {
            float v = sv[c]; int n = si[c];
#pragma unroll
            for (int p = 0; p < T_CAND; ++p) {
                if (v > v16[p]) {
                    float tv = v16[p]; v16[p] = v; v = tv;
                    int ti = i16[p]; i16[p] = n; n = ti;
                }
            }
        }
#pragma unroll
        for (int m = 0; m < T_CAND; ++m) ci[m] = i16[m];
    }
    __syncthreads();

    // exact f32 rescore; wave w -> candidates w*4..w*4+3
    {
        const int w = t >> 6, lane = t & 63;
        for (int cc = 0; cc < 4; ++cc) {
            int c = w * 4 + cc;
            int row = ci[c];
            const float* kp = ke + (size_t)row * DD + lane * 12;
            const float* qp = q + qi * DD + lane * 12;
            float d = 0.f, ks = 0.f;
#pragma unroll
            for (int i = 0; i < 12; ++i) {
                float kv = kp[i];
                d = fmaf(qp[i], kv, d);
                ks = fmaf(kv, kv, ks);
            }
#pragma unroll
            for (int off = 32; off > 0; off >>= 1) {
                d += __shfl_xor(d, off, 64);
                ks += __shfl_xor(ks, off, 64);
            }
            if (lane == 0)
                cs_[c] = d / fmaxf(qn[qi] * sqrtf(ks), 1e-8f);
        }
    }
    __syncthreads();

    // final top-5 of 16 (tie -> lower index)
    if (t == 0) {
        float v5[K_TOP]; int i5[K_TOP];
#pragma unroll
        for (int m = 0; m < K_TOP; ++m) { v5[m] = -FLT_MAX; i5[m] = INT_MAX; }
        for (int c = 0; c < T_CAND; ++c) {
            float v = cs_[c]; int n = ci[c];
#pragma unroll
            for (int m = 0; m < K_TOP; ++m) {
                bool take = (v > v5[m]) || (v == v5[m] && n < i5[m]);
                if (take) {
                    float tv = v5[m]; v5[m] = v; v = tv;
                    int ti = i5[m]; i5[m] = n; n = ti;
                }
            }
        }
#pragma unroll
        for (int m = 0; m < K_TOP; ++m) fi[m] = i5[m];
    }
    __syncthreads();

    // gather knowledge_full rows (ints < 30000 exact in f32)
    for (int pos = t; pos < K_TOP * LK; pos += 256) {
        int m = pos >> 5, lgi = pos & 31;
        out[(qi * K_TOP + m) * LK + lgi] = (float)kf[(size_t)fi[m] * LK + lgi];
    }
    // gather embed rows
    const int EO = BQ * K_TOP * LK;  // 10240
    for (int m = 0; m < K_TOP; ++m) {
        const float4* srcp = (const float4*)(ke + (size_t)fi[m] * DD);
        float4* dstp = (float4*)(out + EO + (size_t)(qi * K_TOP + m) * DD);
        for (int pos = t; pos < DD / 4; pos += 256) dstp[pos] = srcp[pos];
    }
}

extern "C" void kernel_launch(void* const* d_in, const int* in_sizes, int n_in,
                              void* d_out, int out_size, void* d_ws, size_t ws_size,
                              hipStream_t stream) {
    const float* query = (const float*)d_in[0];
    const float* ke    = (const float*)d_in[1];
    const int*   kf    = (const int*)d_in[2];
    float* out = (float*)d_out;

    // ws layout: simsO [64][100032] f32 (25.6 MB) | pv2 [64][8][8] float2 | qn[64] | qbf[64*768] ushort
    float*  simsO = (float*)d_ws;
    float2* pv2   = (float2*)((char*)d_ws + (size_t)BQ * SST * sizeof(float));
    float*  qn    = (float*)((char*)pv2 + (size_t)BQ * NCH * M_CH * sizeof(float2));
    ushort* qbf   = (ushort*)(qn + 64);

    prep_kernel<<<BQ, 256, 0, stream>>>(query, qbf, qn);
    sims_kernel<<<NB, 256, 0, stream>>>(qbf, ke, simsO);
    scan_kernel<<<BQ * NCH, 256, 0, stream>>>(simsO, pv2);
    rescore_kernel<<<BQ, 256, 0, stream>>>(pv2, query, ke, kf, qn, out);
}

// Round 5
// 232.461 us; speedup vs baseline: 1.1115x; 1.1115x over previous
//
#include <hip/hip_runtime.h>
#include <cfloat>
#include <climits>

// Retriever: cosine-sim top-5 over 100k knowledge vectors + gather.
// v5: one-pass. Each block stages 32 ke rows f32 -> normalized bf16 into LDS
// (norms fused into conversion), then a barrier-free bf16-MFMA K-loop writes
// cosine sims to ws. Chunked scan -> top-16 -> exact f32 rescore -> top-5.

#define BQ 64
#define DD 768
#define NK 100000
#define LK 32
#define K_TOP 5
#define BNR 32                      // knowledge rows per block
#define NBLK (NK / BNR)             // 3125 (exact)
#define NCH 8                       // scan chunks per query
#define CHN (NK / NCH)              // 12500
#define M_CH 8                      // per-chunk top-M
#define T_CAND 16                   // rescore candidate count

typedef __attribute__((ext_vector_type(8))) short short8;
typedef __attribute__((ext_vector_type(4))) float f32x4;

static __device__ __forceinline__ ushort bf16_rtn(float x) {
    uint u = __float_as_uint(x);
    return (ushort)((u + 0x7FFFu + ((u >> 16) & 1u)) >> 16);
}

// ---------- phase 0: query -> normalized bf16 + exact f32 norm ----------
__global__ __launch_bounds__(256) void prep_kernel(const float* __restrict__ q,
                                                   ushort* __restrict__ qbf,
                                                   float* __restrict__ qn) {
    const int b = blockIdx.x, t = threadIdx.x;
    __shared__ float red[4];
    float v[3];
    float s = 0.f;
#pragma unroll
    for (int i = 0; i < 3; ++i) {
        v[i] = q[b * DD + t + i * 256];
        s = fmaf(v[i], v[i], s);
    }
    for (int off = 32; off > 0; off >>= 1) s += __shfl_down(s, off, 64);
    if ((t & 63) == 0) red[t >> 6] = s;
    __syncthreads();
    const float tot = red[0] + red[1] + red[2] + red[3];
    const float rq = rsqrtf(tot);
#pragma unroll
    for (int i = 0; i < 3; ++i)
        qbf[b * DD + t + i * 256] = bf16_rtn(v[i] * rq);
    if (t == 0) qn[b] = sqrtf(tot);
}

// ---------- phase 1: stage->LDS + bf16 MFMA, sims to ws ----------
// 3125 blocks x 4 waves. Block: 64q x 32n. Wave: 32q x 16n (wq=w>>1, wn=w&1).
__global__ __launch_bounds__(256) void sims_kernel(const ushort* __restrict__ qbf,
                                                   const float* __restrict__ ke,
                                                   float* __restrict__ simsO) {
    __shared__ ushort Bs[BNR * DD];   // 49152 B, rows XOR-swizzled by ((row&7)<<4)

    const int t = threadIdx.x;
    const int w = t >> 6, l = t & 63;
    const int lg = l >> 4, li = l & 15;
    const int wq = w >> 1, wn = w & 1;
    const int n0 = blockIdx.x * BNR;

    // ---- stage 8 rows per wave: read f32 (1KB/instr), normalize, bf16 -> LDS ----
    {
        const int r0 = w * 8;
        const float* src = ke + (size_t)(n0 + r0) * DD + l * 4;
        f32x4 c0 = *(const f32x4*)(src);
        f32x4 c1 = *(const f32x4*)(src + 256);
        f32x4 c2 = *(const f32x4*)(src + 512);
        char* bp = (char*)Bs;
#pragma unroll
        for (int i = 0; i < 8; ++i) {
            f32x4 x0, x1, x2;
            if (i < 7) {               // prefetch next row (2-deep pipeline)
                const float* s2 = src + (size_t)(i + 1) * DD;
                x0 = *(const f32x4*)(s2);
                x1 = *(const f32x4*)(s2 + 256);
                x2 = *(const f32x4*)(s2 + 512);
            }
            float s = 0.f;
#pragma unroll
            for (int j = 0; j < 4; ++j) {
                s = fmaf(c0[j], c0[j], s);
                s = fmaf(c1[j], c1[j], s);
                s = fmaf(c2[j], c2[j], s);
            }
#pragma unroll
            for (int off = 1; off < 64; off <<= 1) s += __shfl_xor(s, off, 64);
            const float rk = rsqrtf(s);
            const int row = r0 + i;
            const int base = row * 1536 + l * 8;
            const int sw = (row & 7) << 4;
            ushort4 u0, u1, u2;
            u0 = make_ushort4(bf16_rtn(c0[0] * rk), bf16_rtn(c0[1] * rk),
                              bf16_rtn(c0[2] * rk), bf16_rtn(c0[3] * rk));
            u1 = make_ushort4(bf16_rtn(c1[0] * rk), bf16_rtn(c1[1] * rk),
                              bf16_rtn(c1[2] * rk), bf16_rtn(c1[3] * rk));
            u2 = make_ushort4(bf16_rtn(c2[0] * rk), bf16_rtn(c2[1] * rk),
                              bf16_rtn(c2[2] * rk), bf16_rtn(c2[3] * rk));
            *(ushort4*)(bp + ((base)        ^ sw)) = u0;
            *(ushort4*)(bp + ((base + 512)  ^ sw)) = u1;
            *(ushort4*)(bp + ((base + 1024) ^ sw)) = u2;
            if (i < 7) { c0 = x0; c1 = x1; c2 = x2; }
        }
    }
    __syncthreads();

    // ---- K-loop: 24 steps, 2 MFMA + 1 ds_read_b128 + 2 A-loads per step ----
    const ushort* aptr0 = qbf + (wq * 32 + li) * DD + lg * 8;
    const ushort* aptr1 = qbf + (wq * 32 + 16 + li) * DD + lg * 8;
    const char* bbase = (const char*)Bs;
    const int boff = (wn * 16 + li) * 1536 + lg * 16;
    const int bsw = (li & 7) << 4;

    f32x4 acc0 = (f32x4){0.f, 0.f, 0.f, 0.f};
    f32x4 acc1 = (f32x4){0.f, 0.f, 0.f, 0.f};
    short8 a0[4], a1[4], br[2];

#pragma unroll
    for (int p = 0; p < 3; ++p) {            // A ring-4 preload (L2 ~200cy)
        a0[p] = *(const short8*)(aptr0 + p * 32);
        a1[p] = *(const short8*)(aptr1 + p * 32);
    }
    br[0] = *(const short8*)(bbase + (boff ^ bsw));

#pragma unroll
    for (int kt = 0; kt < 24; ++kt) {
        const int ca = kt & 3, cb = kt & 1;
        if (kt < 21) {
            a0[(kt + 3) & 3] = *(const short8*)(aptr0 + (kt + 3) * 32);
            a1[(kt + 3) & 3] = *(const short8*)(aptr1 + (kt + 3) * 32);
        }
        if (kt < 23)
            br[cb ^ 1] = *(const short8*)(bbase + ((boff + (kt + 1) * 64) ^ bsw));
        acc0 = __builtin_amdgcn_mfma_f32_16x16x32_bf16(a0[ca], br[cb], acc0, 0, 0, 0);
        acc1 = __builtin_amdgcn_mfma_f32_16x16x32_bf16(a1[ca], br[cb], acc1, 0, 0, 0);
    }

    // ---- store sims (C layout: col=lane&15, row=(lane>>4)*4+reg) ----
    const int ncol = n0 + wn * 16 + li;
    float* orow = simsO + ncol;
#pragma unroll
    for (int r = 0; r < 4; ++r)
        orow[(size_t)(wq * 32 + lg * 4 + r) * NK] = acc0[r];
#pragma unroll
    for (int r = 0; r < 4; ++r)
        orow[(size_t)(wq * 32 + 16 + lg * 4 + r) * NK] = acc1[r];
}

// ---------- phase 2: chunked top-8 scan of sims buffer ----------
#define INS8(v, n, va, ia)                                                  \
    _Pragma("unroll")                                                       \
    for (int m_ = 0; m_ < 8; ++m_) {                                        \
        if ((v) > va[m_]) {                                                 \
            float tv_ = va[m_]; va[m_] = (v); (v) = tv_;                    \
            int ti_ = ia[m_]; ia[m_] = (n); (n) = ti_;                      \
        }                                                                   \
    }

__global__ __launch_bounds__(256) void scan_kernel(const float* __restrict__ simsO,
                                                   float2* __restrict__ pv2) {
    const int t = threadIdx.x;
    const int q = blockIdx.x >> 3, c = blockIdx.x & 7;
    const int base = c * CHN;

    float v8[8]; int i8[8];
#pragma unroll
    for (int m = 0; m < 8; ++m) { v8[m] = -FLT_MAX; i8[m] = INT_MAX; }

    const float4* row = (const float4*)(simsO + (size_t)q * NK + base);
    for (int i4 = t; i4 < CHN / 4; i4 += 256) {   // 3125 float4s
        float4 vv = row[i4];
        int nb = base + i4 * 4;
        float v; int n;
        v = vv.x; n = nb + 0; INS8(v, n, v8, i8);
        v = vv.y; n = nb + 1; INS8(v, n, v8, i8);
        v = vv.z; n = nb + 2; INS8(v, n, v8, i8);
        v = vv.w; n = nb + 3; INS8(v, n, v8, i8);
    }

    __shared__ float sv[256][8];
    __shared__ int   si[256][8];
#pragma unroll
    for (int m = 0; m < 8; ++m) { sv[t][m] = v8[m]; si[t][m] = i8[m]; }
    __syncthreads();

    for (int active = 64; active >= 1; active >>= 2) {
        if (t < active) {
#pragma unroll
            for (int m = 0; m < 8; ++m) { v8[m] = -FLT_MAX; i8[m] = INT_MAX; }
            for (int s = 0; s < 4; ++s) {
                int rrow = t * 4 + s;
#pragma unroll
                for (int m = 0; m < 8; ++m) {
                    float v = sv[rrow][m]; int n = si[rrow][m];
                    INS8(v, n, v8, i8);
                }
            }
        }
        __syncthreads();
        if (t < active) {
#pragma unroll
            for (int m = 0; m < 8; ++m) { sv[t][m] = v8[m]; si[t][m] = i8[m]; }
        }
        __syncthreads();
    }

    if (t < M_CH)
        pv2[((size_t)q * NCH + c) * M_CH + t] =
            make_float2(sv[0][t], __int_as_float(si[0][t]));
}

// ---------- phase 3: merge 64 -> top-16 -> exact f32 rescore -> top-5 -> gather ----------
__global__ __launch_bounds__(256) void rescore_kernel(
    const float2* __restrict__ pv2,
    const float* __restrict__ q, const float* __restrict__ ke,
    const int* __restrict__ kf, const float* __restrict__ qn,
    float* __restrict__ out) {
    const int qi = blockIdx.x, t = threadIdx.x;
    __shared__ float sv[64];
    __shared__ int   si[64];
    __shared__ int   ci[T_CAND];
    __shared__ float cs_[T_CAND];
    __shared__ int   fi[K_TOP];

    if (t < NCH * M_CH) {
        float2 e = pv2[(size_t)qi * NCH * M_CH + t];
        sv[t] = e.x; si[t] = __float_as_int(e.y);
    }
    __syncthreads();

    if (t == 0) {
        float v16[T_CAND]; int i16[T_CAND];
#pragma unroll
        for (int m = 0; m < T_CAND; ++m) { v16[m] = -FLT_MAX; i16[m] = INT_MAX; }
        for (int c = 0; c < NCH * M_CH; ++c) {
            float v = sv[c]; int n = si[c];
#pragma unroll
            for (int p = 0; p < T_CAND; ++p) {
                if (v > v16[p]) {
                    float tv = v16[p]; v16[p] = v; v = tv;
                    int ti = i16[p]; i16[p] = n; n = ti;
                }
            }
        }
#pragma unroll
        for (int m = 0; m < T_CAND; ++m) ci[m] = i16[m];
    }
    __syncthreads();

    // exact f32 rescore; wave w -> candidates w*4..w*4+3
    {
        const int w = t >> 6, lane = t & 63;
        for (int cc = 0; cc < 4; ++cc) {
            int c = w * 4 + cc;
            int row = ci[c];
            const float* kp = ke + (size_t)row * DD + lane * 12;
            const float* qp = q + qi * DD + lane * 12;
            float d = 0.f, ks = 0.f;
#pragma unroll
            for (int i = 0; i < 12; ++i) {
                float kv = kp[i];
                d = fmaf(qp[i], kv, d);
                ks = fmaf(kv, kv, ks);
            }
#pragma unroll
            for (int off = 32; off > 0; off >>= 1) {
                d += __shfl_xor(d, off, 64);
                ks += __shfl_xor(ks, off, 64);
            }
            if (lane == 0)
                cs_[c] = d / fmaxf(qn[qi] * sqrtf(ks), 1e-8f);
        }
    }
    __syncthreads();

    // final top-5 of 16 (tie -> lower index)
    if (t == 0) {
        float v5[K_TOP]; int i5[K_TOP];
#pragma unroll
        for (int m = 0; m < K_TOP; ++m) { v5[m] = -FLT_MAX; i5[m] = INT_MAX; }
        for (int c = 0; c < T_CAND; ++c) {
            float v = cs_[c]; int n = ci[c];
#pragma unroll
            for (int m = 0; m < K_TOP; ++m) {
                bool take = (v > v5[m]) || (v == v5[m] && n < i5[m]);
                if (take) {
                    float tv = v5[m]; v5[m] = v; v = tv;
                    int ti = i5[m]; i5[m] = n; n = ti;
                }
            }
        }
#pragma unroll
        for (int m = 0; m < K_TOP; ++m) fi[m] = i5[m];
    }
    __syncthreads();

    // gather knowledge_full rows (ints < 30000 exact in f32)
    for (int pos = t; pos < K_TOP * LK; pos += 256) {
        int m = pos >> 5, lgi = pos & 31;
        out[(qi * K_TOP + m) * LK + lgi] = (float)kf[(size_t)fi[m] * LK + lgi];
    }
    // gather embed rows
    const int EO = BQ * K_TOP * LK;  // 10240
    for (int m = 0; m < K_TOP; ++m) {
        const float4* srcp = (const float4*)(ke + (size_t)fi[m] * DD);
        float4* dstp = (float4*)(out + EO + (size_t)(qi * K_TOP + m) * DD);
        for (int pos = t; pos < DD / 4; pos += 256) dstp[pos] = srcp[pos];
    }
}

extern "C" void kernel_launch(void* const* d_in, const int* in_sizes, int n_in,
                              void* d_out, int out_size, void* d_ws, size_t ws_size,
                              hipStream_t stream) {
    const float* query = (const float*)d_in[0];
    const float* ke    = (const float*)d_in[1];
    const int*   kf    = (const int*)d_in[2];
    float* out = (float*)d_out;

    // ws layout: simsO [64][100000] f32 (25.6 MB) | pv2 [64][64] float2 | qn[64] | qbf[64*768] ushort
    float*  simsO = (float*)d_ws;
    float2* pv2   = (float2*)((char*)d_ws + (size_t)BQ * NK * sizeof(float));
    float*  qn    = (float*)((char*)pv2 + (size_t)BQ * NCH * M_CH * sizeof(float2));
    ushort* qbf   = (ushort*)(qn + 64);

    prep_kernel<<<BQ, 256, 0, stream>>>(query, qbf, qn);
    sims_kernel<<<NBLK, 256, 0, stream>>>(qbf, ke, simsO);
    scan_kernel<<<BQ * NCH, 256, 0, stream>>>(simsO, pv2);
    rescore_kernel<<<BQ, 256, 0, stream>>>(pv2, query, ke, kf, qn, out);
}